// Round 1
// baseline (763.450 us; speedup 1.0000x reference)
//
#include <hip/hip_runtime.h>

#define NODE 30000
#define HID 128
#define NE 600000
#define NB 4096
#define NROWS 8192

typedef short bf16x8 __attribute__((ext_vector_type(8)));
typedef float f32x4 __attribute__((ext_vector_type(4)));
typedef unsigned short u16x8 __attribute__((ext_vector_type(8)));

__device__ __forceinline__ unsigned short f2bf(float x) {
  union { float f; unsigned u; } v; v.f = x;
  unsigned r = v.u + 0x7fffu + ((v.u >> 16) & 1u);
  return (unsigned short)(r >> 16);
}
__device__ __forceinline__ float bf2f(unsigned short h) {
  union { unsigned u; float f; } v; v.u = ((unsigned)h) << 16; return v.f;
}

// ---------------- K1: degree count ----------------
__global__ void k_deg(const int* __restrict__ rows, int* __restrict__ deg) {
  int e = blockIdx.x * 256 + threadIdx.x;
  if (e < NE) atomicAdd(&deg[rows[e]], 1);
}

// ---------------- K2: exclusive scan (single block) + winv ----------------
__global__ void __launch_bounds__(1024) k_scan(const int* __restrict__ deg,
                                               int* __restrict__ off,
                                               float* __restrict__ winv) {
  __shared__ int part[1024];
  int t = threadIdx.x;
  int base = t * 30;
  int s = 0;
  for (int i = 0; i < 30; i++) { int idx = base + i; if (idx < NODE) s += deg[idx]; }
  part[t] = s; __syncthreads();
  for (int d = 1; d < 1024; d <<= 1) {
    int v = (t >= d) ? part[t - d] : 0;
    __syncthreads();
    part[t] += v;
    __syncthreads();
  }
  int run = (t == 0) ? 0 : part[t - 1];
  for (int i = 0; i < 30; i++) {
    int idx = base + i;
    if (idx < NODE) {
      off[idx] = run;
      int d = deg[idx];
      run += d;
      winv[idx] = 1.0f / (float)(d > 0 ? d : 1);
    }
  }
  if (t == 1023) off[NODE] = run;
}

// ---------------- K3: scatter edges into CSR buckets ----------------
__global__ void k_scatter(const int* __restrict__ rows, const int* __restrict__ cols,
                          const int* __restrict__ off, int* __restrict__ cursor,
                          int* __restrict__ colidx) {
  int e = blockIdx.x * 256 + threadIdx.x;
  if (e < NE) {
    int r = rows[e];
    int p = atomicAdd(&cursor[r], 1);
    colidx[off[r] + p] = cols[e];
  }
}

// ---------------- K4: per-row aggregation (1 wave = 1 row) ----------------
__global__ void __launch_bounds__(256) k_aggregate(const float* __restrict__ emb,
    const int* __restrict__ off, const int* __restrict__ colidx,
    const float* __restrict__ winv, float* __restrict__ feat32,
    unsigned short* __restrict__ featb, float* __restrict__ sqn) {
  int wv = threadIdx.x >> 6, lane = threadIdx.x & 63;
  int r = blockIdx.x * 4 + wv;
  int e0 = off[r], e1 = off[r + 1];
  float a0 = 0.f, a1 = 0.f;
  for (int e = e0; e < e1; e++) {
    int c = colidx[e];
    float2 v = *(const float2*)(emb + (size_t)c * HID + lane * 2);
    a0 += v.x; a1 += v.y;
  }
  float w = winv[r];
  a0 *= w; a1 *= w;
  float2 o; o.x = a0; o.y = a1;
  *(float2*)(feat32 + (size_t)r * HID + lane * 2) = o;
  ushort2 hb; hb.x = f2bf(a0); hb.y = f2bf(a1);
  *(ushort2*)(featb + (size_t)r * HID + lane * 2) = hb;
  float ss = a0 * a0 + a1 * a1;
  for (int m = 1; m < 64; m <<= 1) ss += __shfl_xor(ss, m);
  if (lane == 0) sqn[r] = ss;
}

// ---------------- K5: node stats: G = feat^T feat, Fsum, h, S1, S2 ----------------
__global__ void __launch_bounds__(256) k_nodestats(const unsigned short* __restrict__ featb,
    const float* __restrict__ sqn, float* __restrict__ G,
    double* __restrict__ Fsum, double* __restrict__ Hsum, double* __restrict__ S12) {
  __shared__ unsigned short lds[128 * 136];
  __shared__ double red[256];
  int t = threadIdx.x;
  int n0 = blockIdx.x * 128;
  {
    int n = t >> 1, h = t & 1;
    unsigned short* dst = lds + n * 136 + h * 64;
    if (n0 + n < NODE) {
      const unsigned short* src = featb + (size_t)(n0 + n) * HID + h * 64;
      #pragma unroll
      for (int i = 0; i < 64; i += 8) *(u16x8*)(dst + i) = *(const u16x8*)(src + i);
    } else {
      u16x8 z = {0, 0, 0, 0, 0, 0, 0, 0};
      #pragma unroll
      for (int i = 0; i < 64; i += 8) *(u16x8*)(dst + i) = z;
    }
  }
  __syncthreads();
  // Gram: 8x8 register tile per thread
  int i0 = (t >> 4) * 8, j0 = (t & 15) * 8;
  float acc[8][8];
  #pragma unroll
  for (int i = 0; i < 8; i++)
    #pragma unroll
    for (int j = 0; j < 8; j++) acc[i][j] = 0.f;
  for (int r = 0; r < 128; r++) {
    const unsigned short* row = lds + r * 136;
    u16x8 va = *(const u16x8*)(row + i0);
    u16x8 vb = *(const u16x8*)(row + j0);
    float ai[8], aj[8];
    #pragma unroll
    for (int k = 0; k < 8; k++) { ai[k] = bf2f(va[k]); aj[k] = bf2f(vb[k]); }
    #pragma unroll
    for (int i = 0; i < 8; i++)
      #pragma unroll
      for (int j = 0; j < 8; j++) acc[i][j] = fmaf(ai[i], aj[j], acc[i][j]);
  }
  #pragma unroll
  for (int i = 0; i < 8; i++)
    #pragma unroll
    for (int j = 0; j < 8; j++) atomicAdd(&G[(i0 + i) * 128 + (j0 + j)], acc[i][j]);
  // Fsum / Hsum / S1 / S2
  int d = t & 127, hh = t >> 7;
  double fs = 0.0, hs = 0.0, s1 = 0.0, s2 = 0.0;
  for (int n = hh * 64; n < hh * 64 + 64; n++) {
    int gn = n0 + n;
    if (gn >= NODE) break;
    float v = bf2f(lds[n * 136 + d]);
    float q = sqn[gn];
    fs += (double)v;
    hs += (double)q * (double)v;
    if (d == 0) { s1 += (double)q; s2 += (double)q * (double)q; }
  }
  red[t] = fs; __syncthreads();
  if (hh == 0) atomicAdd(&Fsum[d], red[t] + red[t + 128]);
  __syncthreads();
  red[t] = hs; __syncthreads();
  if (hh == 0) atomicAdd(&Hsum[d], red[t] + red[t + 128]);
  if (t == 0) { atomicAdd(&S12[0], s1); atomicAdd(&S12[1], s2); }
  if (t == 128) { atomicAdd(&S12[0], s1); atomicAdd(&S12[1], s2); }
}

// ---------------- K6: per-pair analytic mean/std/coeffs (f64) ----------------
__global__ void __launch_bounds__(64) k_pairstats(const int* __restrict__ tp,
    const float* __restrict__ feat32, const float* __restrict__ sqn,
    const float* __restrict__ G, const double* __restrict__ Fsum,
    const double* __restrict__ Hsum, const double* __restrict__ S12,
    float* __restrict__ coefA, float* __restrict__ coefG, float* __restrict__ corr) {
  __shared__ float shl[128], shr[128];
  int b = blockIdx.x, lane = threadIdx.x;
  int l = tp[2 * b], r = tp[2 * b + 1];
  float2 lv = *(const float2*)(feat32 + (size_t)l * HID + lane * 2);
  float2 rv = *(const float2*)(feat32 + (size_t)r * HID + lane * 2);
  shl[lane * 2] = lv.x; shl[lane * 2 + 1] = lv.y;
  shr[lane * 2] = rv.x; shr[lane * 2 + 1] = rv.y;
  __syncthreads();
  float dx = lv.x - rv.x, dy = lv.y - rv.y;
  float ps = dx * dx + dy * dy;
  for (int m = 1; m < 64; m <<= 1) ps += __shfl_xor(ps, m);
  // q = G * vec (G symmetric), coalesced over G rows
  double ql0 = 0, ql1 = 0, qr0 = 0, qr1 = 0;
  for (int j = 0; j < 128; j++) {
    float2 g = *(const float2*)(G + (size_t)j * 128 + lane * 2);
    double slj = (double)shl[j], srj = (double)shr[j];
    ql0 += (double)g.x * slj; ql1 += (double)g.y * slj;
    qr0 += (double)g.x * srj; qr1 += (double)g.y * srj;
  }
  double lx0 = lv.x, lx1 = lv.y, rx0 = rv.x, rx1 = rv.y;
  double lG = lx0 * ql0 + lx1 * ql1;
  double rG = rx0 * qr0 + rx1 * qr1;
  double f0 = Fsum[lane * 2], f1 = Fsum[lane * 2 + 1];
  double h0 = Hsum[lane * 2], h1 = Hsum[lane * 2 + 1];
  double lF = lx0 * f0 + lx1 * f1, rF = rx0 * f0 + rx1 * f1;
  double lH = lx0 * h0 + lx1 * h1, rH = rx0 * h0 + rx1 * h1;
  for (int m = 1; m < 64; m <<= 1) {
    lG += __shfl_xor(lG, m); rG += __shfl_xor(rG, m);
    lF += __shfl_xor(lF, m); rF += __shfl_xor(rF, m);
    lH += __shfl_xor(lH, m); rH += __shfl_xor(rH, m);
  }
  if (lane == 0) {
    const double GAM = 3.0, LAM = 30.0;
    double pos = (double)ps;
    double S1 = S12[0], S2 = S12[1];
    double sl = (double)sqn[l], sr = (double)sqn[r];
    double N = (double)NODE;
    for (int side = 0; side < 2; side++) {
      double u  = pos + GAM - (side ? sr : sl);
      double F  = side ? rF : lF;
      double Gq = side ? rG : lG;
      double H  = side ? rH : lH;
      double Sx  = N * u - S1 + 2.0 * F;
      double Sxx = N * u * u + S2 + 4.0 * Gq - 2.0 * u * S1 + 4.0 * u * F - 4.0 * H;
      double xl = pos + GAM;   // unmasked value at j==l (exact identity)
      double xr2 = GAM;        // unmasked value at j==r (exact identity)
      double Sxm, Sxxm;
      if (l != r) { Sxm = Sx - xl - xr2; Sxxm = Sxx - xl * xl - xr2 * xr2; }
      else        { Sxm = Sx - 2.0 * GAM; Sxxm = Sxx; }
      double mn = Sxm / N;
      double var = Sxxm / N - mn * mn;
      double sd = sqrt(var);
      double alpha = 2.0 * LAM / sd;
      double g2 = LAM * (u - mn) / sd;
      double cr;
      if (l != r)
        cr = exp(LAM * (xl - mn) / sd) + exp(LAM * (GAM - mn) / sd)
             - 2.0 * exp(LAM * (0.0 - mn) / sd);
      else
        cr = exp(LAM * (GAM - mn) / sd) - exp(LAM * (-GAM - mn) / sd);
      int row = b + side * NB;
      coefA[row] = (float)alpha;
      coefG[row] = (float)g2;
      corr[row]  = (float)cr;
    }
  }
}

// ---------------- K7: fused bf16-MFMA GEMM + exp-sum ----------------
// 64 m-rows per wave (A in regs), B fragments streamed from global bf16,
// chunk-major block order for L2 locality. 25 chunks x 75 tiles of 16 nodes.
__global__ void k_fused(const int* __restrict__ tp, const float* __restrict__ feat32,
    const unsigned short* __restrict__ featb, const float* __restrict__ sqn,
    const float* __restrict__ coefA, const float* __restrict__ coefG,
    float* __restrict__ lsum) {
  int wv = threadIdx.x >> 6, lane = threadIdx.x & 63;
  int g = blockIdx.x * 4 + wv;       // 0..3199
  int chunk = g >> 7;                // 0..24 (consecutive blocks share chunk)
  int mw = g & 127;                  // 0..127 (64 rows each)
  int quad = lane >> 4, c16 = lane & 15;

  bf16x8 af[4][4];
  float cA[4][4], cG[4][4];
  #pragma unroll
  for (int f = 0; f < 4; f++) {
    int row = mw * 64 + f * 16 + c16;
    int node = (row < NB) ? tp[2 * row] : tp[2 * (row - NB) + 1];
    const float* src = feat32 + (size_t)node * HID + quad * 8;
    #pragma unroll
    for (int kc = 0; kc < 4; kc++) {
      float4 v0 = *(const float4*)(src + kc * 32);
      float4 v1 = *(const float4*)(src + kc * 32 + 4);
      bf16x8 a;
      a[0] = (short)f2bf(v0.x); a[1] = (short)f2bf(v0.y);
      a[2] = (short)f2bf(v0.z); a[3] = (short)f2bf(v0.w);
      a[4] = (short)f2bf(v1.x); a[5] = (short)f2bf(v1.y);
      a[6] = (short)f2bf(v1.z); a[7] = (short)f2bf(v1.w);
      af[f][kc] = a;
    }
    int cr0 = mw * 64 + f * 16 + quad * 4;
    #pragma unroll
    for (int i = 0; i < 4; i++) { cA[f][i] = coefA[cr0 + i]; cG[f][i] = coefG[cr0 + i]; }
  }
  float acc[4][4];
  #pragma unroll
  for (int f = 0; f < 4; f++)
    #pragma unroll
    for (int i = 0; i < 4; i++) acc[f][i] = 0.f;

  int t0 = chunk * 75;
  for (int t = t0; t < t0 + 75; t++) {
    int j0 = t * 16;
    const unsigned short* bsrc = featb + (size_t)(j0 + c16) * HID + quad * 8;
    bf16x8 b0 = *(const bf16x8*)(bsrc);
    bf16x8 b1 = *(const bf16x8*)(bsrc + 32);
    bf16x8 b2 = *(const bf16x8*)(bsrc + 64);
    bf16x8 b3 = *(const bf16x8*)(bsrc + 96);
    float tsq = -0.5f * sqn[j0 + c16];
    #pragma unroll
    for (int f = 0; f < 4; f++) {
      f32x4 c = {0.f, 0.f, 0.f, 0.f};
      c = __builtin_amdgcn_mfma_f32_16x16x32_bf16(af[f][0], b0, c, 0, 0, 0);
      c = __builtin_amdgcn_mfma_f32_16x16x32_bf16(af[f][1], b1, c, 0, 0, 0);
      c = __builtin_amdgcn_mfma_f32_16x16x32_bf16(af[f][2], b2, c, 0, 0, 0);
      c = __builtin_amdgcn_mfma_f32_16x16x32_bf16(af[f][3], b3, c, 0, 0, 0);
      #pragma unroll
      for (int i = 0; i < 4; i++)
        acc[f][i] += __expf(fmaf(cA[f][i], c[i] + tsq, cG[f][i]));
    }
  }
  #pragma unroll
  for (int f = 0; f < 4; f++)
    #pragma unroll
    for (int i = 0; i < 4; i++) {
      float v = acc[f][i];
      v += __shfl_xor(v, 1); v += __shfl_xor(v, 2);
      v += __shfl_xor(v, 4); v += __shfl_xor(v, 8);
      acc[f][i] = v;
    }
  int f = c16 >> 2, i = c16 & 3;
  int row = mw * 64 + f * 16 + quad * 4 + i;
  atomicAdd(&lsum[row], acc[f][i]);
}

// ---------------- K8: final reduction ----------------
__global__ void __launch_bounds__(1024) k_final(const float* __restrict__ lsum,
    const float* __restrict__ corr, float* __restrict__ out) {
  __shared__ double red[1024];
  int t = threadIdx.x;
  double s = 0.0;
  for (int r = t; r < NROWS; r += 1024) {
    double v = (double)lsum[r] - (double)corr[r];
    s += 10.0 + log(v);   // TAU + log(sum of exp(z))
  }
  red[t] = s; __syncthreads();
  for (int d = 512; d > 0; d >>= 1) { if (t < d) red[t] += red[t + d]; __syncthreads(); }
  if (t == 0) out[0] = (float)(red[0] / (double)NB);
}

extern "C" void kernel_launch(void* const* d_in, const int* in_sizes, int n_in,
                              void* d_out, int out_size, void* d_ws, size_t ws_size,
                              hipStream_t stream) {
  (void)in_sizes; (void)n_in; (void)out_size; (void)ws_size;
  const int* tp    = (const int*)d_in[0];
  const int* adj   = (const int*)d_in[1];
  const float* emb = (const float*)d_in[2];
  const int* rows = adj;
  const int* cols = adj + NE;

  char* ws = (char*)d_ws;
  size_t o = 0;
  auto alloc = [&](size_t bytes) -> char* {
    char* p = ws + o;
    o = (o + bytes + 255) & ~(size_t)255;
    return p;
  };
  // zero-initialized region (single memset)
  int* deg       = (int*)alloc(NODE * 4);
  int* cursor    = (int*)alloc(NODE * 4);
  float* G       = (float*)alloc(128 * 128 * 4);
  double* Fsum   = (double*)alloc(128 * 8);
  double* Hsum   = (double*)alloc(128 * 8);
  double* S12    = (double*)alloc(2 * 8);
  float* lsum    = (float*)alloc(NROWS * 4);
  size_t zero_bytes = o;
  // rest
  int* off       = (int*)alloc((NODE + 1) * 4);
  float* winv    = (float*)alloc(NODE * 4);
  float* sqn     = (float*)alloc(NODE * 4);
  float* coefA   = (float*)alloc(NROWS * 4);
  float* coefG   = (float*)alloc(NROWS * 4);
  float* corr    = (float*)alloc(NROWS * 4);
  int* colidx    = (int*)alloc((size_t)NE * 4);
  float* feat32  = (float*)alloc((size_t)NODE * HID * 4);
  unsigned short* featb = (unsigned short*)alloc((size_t)NODE * HID * 2);

  hipMemsetAsync(d_ws, 0, zero_bytes, stream);
  k_deg<<<(NE + 255) / 256, 256, 0, stream>>>(rows, deg);
  k_scan<<<1, 1024, 0, stream>>>(deg, off, winv);
  k_scatter<<<(NE + 255) / 256, 256, 0, stream>>>(rows, cols, off, cursor, colidx);
  k_aggregate<<<NODE / 4, 256, 0, stream>>>(emb, off, colidx, winv, feat32, featb, sqn);
  k_nodestats<<<235, 256, 0, stream>>>(featb, sqn, G, Fsum, Hsum, S12);
  k_pairstats<<<NB, 64, 0, stream>>>(tp, feat32, sqn, G, Fsum, Hsum, S12, coefA, coefG, corr);
  k_fused<<<800, 256, 0, stream>>>(tp, feat32, featb, sqn, coefA, coefG, lsum);
  k_final<<<1, 1024, 0, stream>>>(lsum, corr, (float*)d_out);
}

// Round 2
// 652.766 us; speedup vs baseline: 1.1696x; 1.1696x over previous
//
#include <hip/hip_runtime.h>

#define NODE 30000
#define HID 128
#define NE 600000
#define NB 4096
#define NROWS 8192

typedef short bf16x8 __attribute__((ext_vector_type(8)));
typedef float f32x4 __attribute__((ext_vector_type(4)));
typedef unsigned short u16x8 __attribute__((ext_vector_type(8)));

__device__ __forceinline__ unsigned short f2bf(float x) {
  union { float f; unsigned u; } v; v.f = x;
  unsigned r = v.u + 0x7fffu + ((v.u >> 16) & 1u);
  return (unsigned short)(r >> 16);
}
__device__ __forceinline__ float bf2f(unsigned short h) {
  union { unsigned u; float f; } v; v.u = ((unsigned)h) << 16; return v.f;
}
__device__ __forceinline__ float fast_exp2(float x) {
#if __has_builtin(__builtin_amdgcn_exp2f)
  return __builtin_amdgcn_exp2f(x);
#else
  return exp2f(x);
#endif
}

// ---------------- K1: degree count ----------------
__global__ void k_deg(const int* __restrict__ rows, int* __restrict__ deg) {
  int e = blockIdx.x * 256 + threadIdx.x;
  if (e < NE) atomicAdd(&deg[rows[e]], 1);
}

// ---------------- K2: exclusive scan (single block) + winv ----------------
__global__ void __launch_bounds__(1024) k_scan(const int* __restrict__ deg,
                                               int* __restrict__ off,
                                               float* __restrict__ winv) {
  __shared__ int part[1024];
  int t = threadIdx.x;
  int base = t * 30;
  int s = 0;
  for (int i = 0; i < 30; i++) { int idx = base + i; if (idx < NODE) s += deg[idx]; }
  part[t] = s; __syncthreads();
  for (int d = 1; d < 1024; d <<= 1) {
    int v = (t >= d) ? part[t - d] : 0;
    __syncthreads();
    part[t] += v;
    __syncthreads();
  }
  int run = (t == 0) ? 0 : part[t - 1];
  for (int i = 0; i < 30; i++) {
    int idx = base + i;
    if (idx < NODE) {
      off[idx] = run;
      int d = deg[idx];
      run += d;
      winv[idx] = 1.0f / (float)(d > 0 ? d : 1);
    }
  }
  if (t == 1023) off[NODE] = run;
}

// ---------------- K3: scatter edges into CSR buckets ----------------
__global__ void k_scatter(const int* __restrict__ rows, const int* __restrict__ cols,
                          const int* __restrict__ off, int* __restrict__ cursor,
                          int* __restrict__ colidx) {
  int e = blockIdx.x * 256 + threadIdx.x;
  if (e < NE) {
    int r = rows[e];
    int p = atomicAdd(&cursor[r], 1);
    colidx[off[r] + p] = cols[e];
  }
}

// ---------------- K4: per-row aggregation (1 wave = 1 row) ----------------
__global__ void __launch_bounds__(256) k_aggregate(const float* __restrict__ emb,
    const int* __restrict__ off, const int* __restrict__ colidx,
    const float* __restrict__ winv, float* __restrict__ feat32,
    unsigned short* __restrict__ featb, float* __restrict__ sqn,
    float* __restrict__ tsqn) {
  int wv = threadIdx.x >> 6, lane = threadIdx.x & 63;
  int r = blockIdx.x * 4 + wv;
  int e0 = off[r], e1 = off[r + 1];
  float a0 = 0.f, a1 = 0.f;
  for (int e = e0; e < e1; e++) {
    int c = colidx[e];
    float2 v = *(const float2*)(emb + (size_t)c * HID + lane * 2);
    a0 += v.x; a1 += v.y;
  }
  float w = winv[r];
  a0 *= w; a1 *= w;
  float2 o; o.x = a0; o.y = a1;
  *(float2*)(feat32 + (size_t)r * HID + lane * 2) = o;
  ushort2 hb; hb.x = f2bf(a0); hb.y = f2bf(a1);
  *(ushort2*)(featb + (size_t)r * HID + lane * 2) = hb;
  float ss = a0 * a0 + a1 * a1;
  for (int m = 1; m < 64; m <<= 1) ss += __shfl_xor(ss, m);
  if (lane == 0) { sqn[r] = ss; tsqn[r] = -0.5f * ss; }
}

// ---------------- K5: node stats: G = feat^T feat, Fsum, h, S1, S2 ----------------
__global__ void __launch_bounds__(256) k_nodestats(const unsigned short* __restrict__ featb,
    const float* __restrict__ sqn, float* __restrict__ G,
    double* __restrict__ Fsum, double* __restrict__ Hsum, double* __restrict__ S12) {
  __shared__ unsigned short lds[128 * 136];
  __shared__ double red[256];
  int t = threadIdx.x;
  int n0 = blockIdx.x * 128;
  {
    int n = t >> 1, h = t & 1;
    unsigned short* dst = lds + n * 136 + h * 64;
    if (n0 + n < NODE) {
      const unsigned short* src = featb + (size_t)(n0 + n) * HID + h * 64;
      #pragma unroll
      for (int i = 0; i < 64; i += 8) *(u16x8*)(dst + i) = *(const u16x8*)(src + i);
    } else {
      u16x8 z = {0, 0, 0, 0, 0, 0, 0, 0};
      #pragma unroll
      for (int i = 0; i < 64; i += 8) *(u16x8*)(dst + i) = z;
    }
  }
  __syncthreads();
  // Gram: 8x8 register tile per thread
  int i0 = (t >> 4) * 8, j0 = (t & 15) * 8;
  float acc[8][8];
  #pragma unroll
  for (int i = 0; i < 8; i++)
    #pragma unroll
    for (int j = 0; j < 8; j++) acc[i][j] = 0.f;
  for (int r = 0; r < 128; r++) {
    const unsigned short* row = lds + r * 136;
    u16x8 va = *(const u16x8*)(row + i0);
    u16x8 vb = *(const u16x8*)(row + j0);
    float ai[8], aj[8];
    #pragma unroll
    for (int k = 0; k < 8; k++) { ai[k] = bf2f(va[k]); aj[k] = bf2f(vb[k]); }
    #pragma unroll
    for (int i = 0; i < 8; i++)
      #pragma unroll
      for (int j = 0; j < 8; j++) acc[i][j] = fmaf(ai[i], aj[j], acc[i][j]);
  }
  #pragma unroll
  for (int i = 0; i < 8; i++)
    #pragma unroll
    for (int j = 0; j < 8; j++) atomicAdd(&G[(i0 + i) * 128 + (j0 + j)], acc[i][j]);
  // Fsum / Hsum / S1 / S2
  int d = t & 127, hh = t >> 7;
  double fs = 0.0, hs = 0.0, s1 = 0.0, s2 = 0.0;
  for (int n = hh * 64; n < hh * 64 + 64; n++) {
    int gn = n0 + n;
    if (gn >= NODE) break;
    float v = bf2f(lds[n * 136 + d]);
    float q = sqn[gn];
    fs += (double)v;
    hs += (double)q * (double)v;
    if (d == 0) { s1 += (double)q; s2 += (double)q * (double)q; }
  }
  red[t] = fs; __syncthreads();
  if (hh == 0) atomicAdd(&Fsum[d], red[t] + red[t + 128]);
  __syncthreads();
  red[t] = hs; __syncthreads();
  if (hh == 0) atomicAdd(&Hsum[d], red[t] + red[t + 128]);
  if (t == 0) { atomicAdd(&S12[0], s1); atomicAdd(&S12[1], s2); }
  if (t == 128) { atomicAdd(&S12[0], s1); atomicAdd(&S12[1], s2); }
}

// ---------------- K6: per-pair analytic mean/std/coeffs (f64), 4 pairs/block ----------------
__global__ void __launch_bounds__(256) k_pairstats(const int* __restrict__ tp,
    const float* __restrict__ feat32, const float* __restrict__ sqn,
    const float* __restrict__ G, const double* __restrict__ Fsum,
    const double* __restrict__ Hsum, const double* __restrict__ S12,
    float* __restrict__ coefA, float* __restrict__ coefG, float* __restrict__ corr) {
  __shared__ float shl[4][128], shr[4][128];
  int wv = threadIdx.x >> 6, lane = threadIdx.x & 63;
  int b = blockIdx.x * 4 + wv;
  int l = tp[2 * b], r = tp[2 * b + 1];
  float2 lv = *(const float2*)(feat32 + (size_t)l * HID + lane * 2);
  float2 rv = *(const float2*)(feat32 + (size_t)r * HID + lane * 2);
  shl[wv][lane * 2] = lv.x; shl[wv][lane * 2 + 1] = lv.y;
  shr[wv][lane * 2] = rv.x; shr[wv][lane * 2 + 1] = rv.y;
  __syncthreads();
  float dx = lv.x - rv.x, dy = lv.y - rv.y;
  float ps = dx * dx + dy * dy;
  for (int m = 1; m < 64; m <<= 1) ps += __shfl_xor(ps, m);
  // q = G * vec (G symmetric), coalesced over G rows
  double ql0 = 0, ql1 = 0, qr0 = 0, qr1 = 0;
  for (int j = 0; j < 128; j++) {
    float2 g = *(const float2*)(G + (size_t)j * 128 + lane * 2);
    double slj = (double)shl[wv][j], srj = (double)shr[wv][j];
    ql0 += (double)g.x * slj; ql1 += (double)g.y * slj;
    qr0 += (double)g.x * srj; qr1 += (double)g.y * srj;
  }
  double lx0 = lv.x, lx1 = lv.y, rx0 = rv.x, rx1 = rv.y;
  double lG = lx0 * ql0 + lx1 * ql1;
  double rG = rx0 * qr0 + rx1 * qr1;
  double f0 = Fsum[lane * 2], f1 = Fsum[lane * 2 + 1];
  double h0 = Hsum[lane * 2], h1 = Hsum[lane * 2 + 1];
  double lF = lx0 * f0 + lx1 * f1, rF = rx0 * f0 + rx1 * f1;
  double lH = lx0 * h0 + lx1 * h1, rH = rx0 * h0 + rx1 * h1;
  for (int m = 1; m < 64; m <<= 1) {
    lG += __shfl_xor(lG, m); rG += __shfl_xor(rG, m);
    lF += __shfl_xor(lF, m); rF += __shfl_xor(rF, m);
    lH += __shfl_xor(lH, m); rH += __shfl_xor(rH, m);
  }
  if (lane == 0) {
    const double GAM = 3.0, LAM = 30.0, L2E = 1.4426950408889634;
    double pos = (double)ps;
    double S1 = S12[0], S2 = S12[1];
    double sl = (double)sqn[l], sr = (double)sqn[r];
    double N = (double)NODE;
    for (int side = 0; side < 2; side++) {
      double u  = pos + GAM - (side ? sr : sl);
      double F  = side ? rF : lF;
      double Gq = side ? rG : lG;
      double H  = side ? rH : lH;
      double Sx  = N * u - S1 + 2.0 * F;
      double Sxx = N * u * u + S2 + 4.0 * Gq - 2.0 * u * S1 + 4.0 * u * F - 4.0 * H;
      double xl = pos + GAM;   // unmasked value at j==l (exact identity)
      double xr2 = GAM;        // unmasked value at j==r (exact identity)
      double Sxm, Sxxm;
      if (l != r) { Sxm = Sx - xl - xr2; Sxxm = Sxx - xl * xl - xr2 * xr2; }
      else        { Sxm = Sx - 2.0 * GAM; Sxxm = Sxx; }
      double mn = Sxm / N;
      double var = Sxxm / N - mn * mn;
      double sd = sqrt(var);
      double alpha = 2.0 * LAM / sd;
      double g2 = LAM * (u - mn) / sd;
      double cr;
      if (l != r)
        cr = exp(LAM * (xl - mn) / sd) + exp(LAM * (GAM - mn) / sd)
             - 2.0 * exp(LAM * (0.0 - mn) / sd);
      else
        cr = exp(LAM * (GAM - mn) / sd) - exp(LAM * (-GAM - mn) / sd);
      int row = b + side * NB;
      coefA[row] = (float)(alpha * L2E);   // pre-scaled for exp2 epilogue
      coefG[row] = (float)(g2 * L2E);
      corr[row]  = (float)cr;
    }
  }
}

// ---------------- K7: fused bf16-MFMA GEMM + exp-sum ----------------
// 64 m-rows per wave (A bf16 in regs), B fragments register-double-buffered
// from global bf16 (L2-resident), chunk-major block order. 25 chunks x 75 tiles.
__global__ void __launch_bounds__(256, 3) k_fused(const int* __restrict__ tp,
    const unsigned short* __restrict__ featb, const float* __restrict__ tsqn,
    const float* __restrict__ coefA, const float* __restrict__ coefG,
    float* __restrict__ lsum) {
  int wv = threadIdx.x >> 6, lane = threadIdx.x & 63;
  int g = blockIdx.x * 4 + wv;       // 0..3199
  int chunk = g >> 7;                // 0..24 (4 waves of a block share a chunk)
  int mw = g & 127;                  // 0..127 (64 rows each)
  int quad = lane >> 4, c16 = lane & 15;

  bf16x8 af[4][4];
  float cA[4][4], cG[4][4];
  #pragma unroll
  for (int f = 0; f < 4; f++) {
    int row = mw * 64 + f * 16 + c16;
    int node = (row < NB) ? tp[2 * row] : tp[2 * (row - NB) + 1];
    const unsigned short* src = featb + (size_t)node * HID + quad * 8;
    #pragma unroll
    for (int kc = 0; kc < 4; kc++)
      af[f][kc] = *(const bf16x8*)(src + kc * 32);
    int cr0 = mw * 64 + f * 16 + quad * 4;
    #pragma unroll
    for (int i = 0; i < 4; i++) { cA[f][i] = coefA[cr0 + i]; cG[f][i] = coefG[cr0 + i]; }
  }
  float acc[4][4];
  #pragma unroll
  for (int f = 0; f < 4; f++)
    #pragma unroll
    for (int i = 0; i < 4; i++) acc[f][i] = 0.f;

  // prefetch tile 0
  const unsigned short* bptr = featb + (size_t)(chunk * 1200 + c16) * HID + quad * 8;
  const float* tptr = tsqn + chunk * 1200 + c16;
  bf16x8 nb0 = *(const bf16x8*)(bptr);
  bf16x8 nb1 = *(const bf16x8*)(bptr + 32);
  bf16x8 nb2 = *(const bf16x8*)(bptr + 64);
  bf16x8 nb3 = *(const bf16x8*)(bptr + 96);
  float ntsq = *tptr;

  for (int t = 0; t < 75; t++) {
    bf16x8 b0 = nb0, b1 = nb1, b2 = nb2, b3 = nb3;
    float tsq = ntsq;
    if (t < 74) {                       // issue next tile's loads early
      bptr += 16 * HID; tptr += 16;
      nb0 = *(const bf16x8*)(bptr);
      nb1 = *(const bf16x8*)(bptr + 32);
      nb2 = *(const bf16x8*)(bptr + 64);
      nb3 = *(const bf16x8*)(bptr + 96);
      ntsq = *tptr;
    }
    #pragma unroll
    for (int f = 0; f < 4; f++) {
      f32x4 c = {0.f, 0.f, 0.f, 0.f};
      c = __builtin_amdgcn_mfma_f32_16x16x32_bf16(af[f][0], b0, c, 0, 0, 0);
      c = __builtin_amdgcn_mfma_f32_16x16x32_bf16(af[f][1], b1, c, 0, 0, 0);
      c = __builtin_amdgcn_mfma_f32_16x16x32_bf16(af[f][2], b2, c, 0, 0, 0);
      c = __builtin_amdgcn_mfma_f32_16x16x32_bf16(af[f][3], b3, c, 0, 0, 0);
      #pragma unroll
      for (int i = 0; i < 4; i++)
        acc[f][i] += fast_exp2(fmaf(cA[f][i], c[i] + tsq, cG[f][i]));
    }
  }
  #pragma unroll
  for (int f = 0; f < 4; f++)
    #pragma unroll
    for (int i = 0; i < 4; i++) {
      float v = acc[f][i];
      v += __shfl_xor(v, 1); v += __shfl_xor(v, 2);
      v += __shfl_xor(v, 4); v += __shfl_xor(v, 8);
      acc[f][i] = v;
    }
  int f = c16 >> 2, i = c16 & 3;
  int row = mw * 64 + f * 16 + quad * 4 + i;
  atomicAdd(&lsum[row], acc[f][i]);
}

// ---------------- K8: final reduction ----------------
__global__ void __launch_bounds__(1024) k_final(const float* __restrict__ lsum,
    const float* __restrict__ corr, float* __restrict__ out) {
  __shared__ double red[1024];
  int t = threadIdx.x;
  double s = 0.0;
  for (int r = t; r < NROWS; r += 1024) {
    double v = (double)lsum[r] - (double)corr[r];
    s += 10.0 + log(v);   // TAU + log(sum of exp(z))
  }
  red[t] = s; __syncthreads();
  for (int d = 512; d > 0; d >>= 1) { if (t < d) red[t] += red[t + d]; __syncthreads(); }
  if (t == 0) out[0] = (float)(red[0] / (double)NB);
}

extern "C" void kernel_launch(void* const* d_in, const int* in_sizes, int n_in,
                              void* d_out, int out_size, void* d_ws, size_t ws_size,
                              hipStream_t stream) {
  (void)in_sizes; (void)n_in; (void)out_size; (void)ws_size;
  const int* tp    = (const int*)d_in[0];
  const int* adj   = (const int*)d_in[1];
  const float* emb = (const float*)d_in[2];
  const int* rows = adj;
  const int* cols = adj + NE;

  char* ws = (char*)d_ws;
  size_t o = 0;
  auto alloc = [&](size_t bytes) -> char* {
    char* p = ws + o;
    o = (o + bytes + 255) & ~(size_t)255;
    return p;
  };
  // zero-initialized region (single memset)
  int* deg       = (int*)alloc(NODE * 4);
  int* cursor    = (int*)alloc(NODE * 4);
  float* G       = (float*)alloc(128 * 128 * 4);
  double* Fsum   = (double*)alloc(128 * 8);
  double* Hsum   = (double*)alloc(128 * 8);
  double* S12    = (double*)alloc(2 * 8);
  float* lsum    = (float*)alloc(NROWS * 4);
  size_t zero_bytes = o;
  // rest
  int* off       = (int*)alloc((NODE + 1) * 4);
  float* winv    = (float*)alloc(NODE * 4);
  float* sqn     = (float*)alloc(NODE * 4);
  float* tsqn    = (float*)alloc(NODE * 4);
  float* coefA   = (float*)alloc(NROWS * 4);
  float* coefG   = (float*)alloc(NROWS * 4);
  float* corr    = (float*)alloc(NROWS * 4);
  int* colidx    = (int*)alloc((size_t)NE * 4);
  float* feat32  = (float*)alloc((size_t)NODE * HID * 4);
  unsigned short* featb = (unsigned short*)alloc((size_t)NODE * HID * 2);

  hipMemsetAsync(d_ws, 0, zero_bytes, stream);
  k_deg<<<(NE + 255) / 256, 256, 0, stream>>>(rows, deg);
  k_scan<<<1, 1024, 0, stream>>>(deg, off, winv);
  k_scatter<<<(NE + 255) / 256, 256, 0, stream>>>(rows, cols, off, cursor, colidx);
  k_aggregate<<<NODE / 4, 256, 0, stream>>>(emb, off, colidx, winv, feat32, featb, sqn, tsqn);
  k_nodestats<<<235, 256, 0, stream>>>(featb, sqn, G, Fsum, Hsum, S12);
  k_pairstats<<<NB / 4, 256, 0, stream>>>(tp, feat32, sqn, G, Fsum, Hsum, S12, coefA, coefG, corr);
  k_fused<<<800, 256, 0, stream>>>(tp, featb, tsqn, coefA, coefG, lsum);
  k_final<<<1, 1024, 0, stream>>>(lsum, corr, (float*)d_out);
}